// Round 5
// baseline (273.143 us; speedup 1.0000x reference)
//
#include <hip/hip_runtime.h>
#include <hip/hip_bf16.h>
#include <hip/hip_cooperative_groups.h>

namespace cg = cooperative_groups;

typedef __attribute__((ext_vector_type(8))) short bf16x8;
typedef __attribute__((ext_vector_type(4))) float f32x4;
typedef __attribute__((ext_vector_type(8))) unsigned short u16x8;

__device__ __forceinline__ unsigned short f2bf(float f) {
  union { float f; unsigned u; } c; c.f = f;
  unsigned u = c.u;
  u = (u + 0x7FFFu + ((u >> 16) & 1u)) >> 16;   // RNE
  return (unsigned short)u;
}

__device__ __forceinline__ void gld_lds16(const void* g, void* l) {
  __builtin_amdgcn_global_load_lds(
      (__attribute__((address_space(1))) unsigned int*)g,
      (__attribute__((address_space(3))) unsigned int*)l,
      16, 0, 0);
}

// ---- conversion job j in [0,7168): shared by coop phase 0 and fallback ----
// [0,4096): x->x16 (2048 elems/block) ; [4096,6144): K->K16 ;
// [6144,7168): V [4096,1024] -> Vt [1024,4096] via 64x64 LDS tile.
__device__ __forceinline__ void cvt_job(
    int j, int tid, unsigned short* smem,
    const float* __restrict__ x, unsigned short* __restrict__ x16,
    const float* __restrict__ Kw, unsigned short* __restrict__ K16,
    const float* __restrict__ Vw, unsigned short* __restrict__ V16t) {
  if (j < 6144) {
    const float* in;
    unsigned short* o;
    int i;
    if (j < 4096) {
      in = x; o = x16; i = (j * 256 + tid) * 8;
    } else {
      in = Kw; o = K16; i = ((j - 4096) * 256 + tid) * 8;
    }
    const float4* p = (const float4*)(in + i);
    float4 a = p[0], bb = p[1];
    u16x8 r;
    r[0] = f2bf(a.x); r[1] = f2bf(a.y); r[2] = f2bf(a.z); r[3] = f2bf(a.w);
    r[4] = f2bf(bb.x); r[5] = f2bf(bb.y); r[6] = f2bf(bb.z); r[7] = f2bf(bb.w);
    *(u16x8*)(o + i) = r;
  } else {
    unsigned short(*t)[65] = (unsigned short(*)[65])smem;
    __syncthreads();  // protect any previous smem use
    const int tile = j - 6144;
    const int p0 = (tile & 63) * 64;
    const int e0 = (tile >> 6) * 64;
    const int tx = tid & 63;
    const int ty = tid >> 6;
#pragma unroll
    for (int i = 0; i < 16; ++i) {
      int p = ty + i * 4;
      t[p][tx] = f2bf(Vw[(size_t)(p0 + p) * 1024 + e0 + tx]);
    }
    __syncthreads();
#pragma unroll
    for (int i = 0; i < 16; ++i) {
      int e = ty + i * 4;
      V16t[(size_t)(e0 + e) * 4096 + p0 + tx] = t[tx][e];
    }
  }
}

// ---- one NT GEMM tile: 128x128, BK=64, bf16 MFMA (m97 structure) ----
// A [M x Kd], B [N x Kd] row-major bf16.
// EPI==0: exp2(scale * A.B^T) -> Pout bf16, atomic row sums -> lsum
// EPI==1: (A.B^T) / lin[row]  -> Cout fp32
template <int EPI>
__device__ __forceinline__ void gemm_tile(
    const unsigned short* __restrict__ A, const unsigned short* __restrict__ B,
    int row0, int col0, int Kd, int N,
    unsigned short* sA, unsigned short* sB,
    unsigned short* __restrict__ Pout, float* __restrict__ lsum,
    float* __restrict__ Cout, const float* __restrict__ lin, float scale) {
  const int tid = threadIdx.x;
  const int lane = tid & 63;
  const int w = tid >> 6;
  const int wm = w >> 1;
  const int wn = w & 1;

  f32x4 acc[4][4] = {};

  // Staging: 1024 16B-chunks/tile; chunk c -> row=c>>3, slot=c&7.
  // XOR swizzle: LDS slot s of row r holds global chunk s^(r&7).
  const unsigned short* pA[4];
  const unsigned short* pB[4];
  char* ldsA[4];
  char* ldsB[4];
#pragma unroll
  for (int j = 0; j < 4; ++j) {
    int c = j * 256 + tid;
    int r = c >> 3;
    int cs = (c & 7) ^ (r & 7);
    pA[j] = A + (size_t)(row0 + r) * Kd + cs * 8;
    pB[j] = B + (size_t)(col0 + r) * Kd + cs * 8;
    int off = (j * 256 + (w << 6)) * 16;  // wave-uniform byte base
    ldsA[j] = (char*)sA + off;
    ldsB[j] = (char*)sB + off;
  }

  // Fragment reads: r = w?*64+mi*16+ml -> r&7 == ml&7, so swizzled address
  // is a per-lane base + mi*2048 immediate.
  const int q = lane >> 4;
  const int ml = lane & 15;
  const char* fA[2];
  const char* fB[2];
#pragma unroll
  for (int ks = 0; ks < 2; ++ks) {
    int cc = (ks * 4 + q) ^ (ml & 7);
    fA[ks] = (const char*)sA + (wm * 64 + ml) * 128 + cc * 16;
    fB[ks] = (const char*)sB + (wn * 64 + ml) * 128 + cc * 16;
  }

  const int kIters = Kd >> 6;
  for (int it = 0; it < kIters; ++it) {
    __syncthreads();
#pragma unroll
    for (int j = 0; j < 4; ++j) {
      gld_lds16(pA[j], ldsA[j]);
      gld_lds16(pB[j], ldsB[j]);
      pA[j] += 64;
      pB[j] += 64;
    }
    __syncthreads();
#pragma unroll
    for (int ks = 0; ks < 2; ++ks) {
      bf16x8 af[4], bfr[4];
#pragma unroll
      for (int mi = 0; mi < 4; ++mi) af[mi] = *(const bf16x8*)(fA[ks] + mi * 2048);
#pragma unroll
      for (int ni = 0; ni < 4; ++ni) bfr[ni] = *(const bf16x8*)(fB[ks] + ni * 2048);
#pragma unroll
      for (int mi = 0; mi < 4; ++mi)
#pragma unroll
        for (int ni = 0; ni < 4; ++ni)
          acc[mi][ni] = __builtin_amdgcn_mfma_f32_16x16x32_bf16(
              af[mi], bfr[ni], acc[mi][ni], 0, 0, 0);
    }
  }

  if constexpr (EPI == 0) {
#pragma unroll
    for (int mi = 0; mi < 4; ++mi) {
#pragma unroll
      for (int j = 0; j < 4; ++j) {
        int gr = row0 + wm * 64 + mi * 16 + q * 4 + j;
        float rsum = 0.f;
#pragma unroll
        for (int ni = 0; ni < 4; ++ni) {
          int gc = col0 + wn * 64 + ni * 16 + ml;
          float p = exp2f(acc[mi][ni][j] * scale);  // scale includes log2(e)
          rsum += p;
          Pout[(size_t)gr * N + gc] = f2bf(p);
        }
        rsum += __shfl_xor(rsum, 1);
        rsum += __shfl_xor(rsum, 2);
        rsum += __shfl_xor(rsum, 4);
        rsum += __shfl_xor(rsum, 8);
        if (ml == 0) atomicAdd(&lsum[gr], rsum);
      }
    }
  } else {
#pragma unroll
    for (int mi = 0; mi < 4; ++mi) {
#pragma unroll
      for (int j = 0; j < 4; ++j) {
        int gr = row0 + wm * 64 + mi * 16 + q * 4 + j;
        float rl = 1.0f / lin[gr];
#pragma unroll
        for (int ni = 0; ni < 4; ++ni) {
          int gc = col0 + wn * 64 + ni * 16 + ml;
          Cout[(size_t)gr * N + gc] = acc[mi][ni][j] * rl;
        }
      }
    }
  }
}

// ---------------- fused persistent cooperative kernel ----------------
__global__ __launch_bounds__(256) void fused_all(
    const float* __restrict__ x, const float* __restrict__ Kw,
    const float* __restrict__ Vw,
    unsigned short* __restrict__ x16, unsigned short* __restrict__ K16,
    unsigned short* __restrict__ V16t, unsigned short* __restrict__ P16,
    float* __restrict__ lsum, float* __restrict__ out) {
  __shared__ __align__(16) unsigned short smem[2 * 128 * 64];
  unsigned short* sA = smem;
  unsigned short* sB = smem + 128 * 64;

  const int b = blockIdx.x;
  const int tid = threadIdx.x;

  // phase 0: conversions + lsum zero
  if (b < 32) lsum[b * 256 + tid] = 0.f;
  for (int j = b; j < 7168; j += 512)
    cvt_job(j, tid, smem, x, x16, Kw, K16, Vw, V16t);

  __threadfence();
  cg::this_grid().sync();

  // phase 1: GEMM1  P = exp(x.K^T/32) ; 2048 tiles = 64m x 32n
  {
    const int m = b >> 3;
    const float sc = 0.03125f * 1.44269504088896340736f;  // (1/32)*log2e
#pragma unroll 1
    for (int t = 0; t < 4; ++t) {
      const int n = (b & 7) * 4 + t;
      gemm_tile<0>(x16, K16, m * 128, n * 128, 1024, 4096, sA, sB,
                   P16, lsum, nullptr, nullptr, sc);
    }
  }

  __threadfence();
  cg::this_grid().sync();

  // phase 2: GEMM2  out = (P.Vt^T)/lsum ; 512 tiles, XCD swizzle
  {
    const int m = ((b >> 6) << 3) | (b & 7);
    const int n = (b >> 3) & 7;
    gemm_tile<1>(P16, V16t, m * 128, n * 128, 4096, 1024, sA, sB,
                 nullptr, nullptr, out, lsum, 1.0f);
  }
}

// ---------------- fallback kernels (round-3 proven path) ----------------
__global__ void cvt_all_k(const float* __restrict__ x, unsigned short* __restrict__ x16,
                          const float* __restrict__ Kw, unsigned short* __restrict__ K16,
                          const float* __restrict__ Vw, unsigned short* __restrict__ V16t,
                          float* __restrict__ lsum) {
  __shared__ __align__(16) unsigned short smem[64 * 65];
  if (blockIdx.x < 32) lsum[blockIdx.x * 256 + threadIdx.x] = 0.f;
  cvt_job(blockIdx.x, threadIdx.x, smem, x, x16, Kw, K16, Vw, V16t);
}

__global__ __launch_bounds__(256) void gemm1_k(
    const unsigned short* __restrict__ A, const unsigned short* __restrict__ B,
    unsigned short* __restrict__ P, float* __restrict__ lsum, float scale) {
  __shared__ __align__(16) unsigned short sA[128 * 64];
  __shared__ __align__(16) unsigned short sB[128 * 64];
  gemm_tile<0>(A, B, blockIdx.y * 128, blockIdx.x * 128, 1024, 4096, sA, sB,
               P, lsum, nullptr, nullptr, scale);
}

__global__ __launch_bounds__(256) void gemm2_k(
    const unsigned short* __restrict__ A, const unsigned short* __restrict__ B,
    float* __restrict__ out, const float* __restrict__ lsum) {
  __shared__ __align__(16) unsigned short sA[128 * 64];
  __shared__ __align__(16) unsigned short sB[128 * 64];
  const int bid = blockIdx.x;
  const int row0 = (((bid >> 6) << 3) | (bid & 7)) * 128;
  const int col0 = ((bid >> 3) & 7) * 128;
  gemm_tile<1>(A, B, row0, col0, 4096, 1024, sA, sB,
               nullptr, nullptr, out, lsum, 1.0f);
}

extern "C" void kernel_launch(void* const* d_in, const int* in_sizes, int n_in,
                              void* d_out, int out_size, void* d_ws,
                              size_t ws_size, hipStream_t stream) {
  const float* x = (const float*)d_in[0];   // [8192,1024]
  const float* Kw = (const float*)d_in[1];  // [4096,1024]
  const float* Vw = (const float*)d_in[2];  // [4096,1024]
  float* out = (float*)d_out;               // [8192,1024]
  char* ws = (char*)d_ws;

  unsigned short* x16  = (unsigned short*)(ws);                   // 16 MB
  unsigned short* K16  = (unsigned short*)(ws + (16u << 20));     //  8 MB
  unsigned short* V16t = (unsigned short*)(ws + (24u << 20));     //  8 MB
  float*          lsum = (float*)(ws + (32u << 20));              // 32 KB
  unsigned short* P16  = (unsigned short*)(ws + (33u << 20));     // 64 MB

  const float sc = 0.03125f * 1.44269504088896340736f;

  // Decide coop vs fallback with host-side queries (graph-capture safe,
  // deterministic -> same work every call).
  int dev = 0;
  (void)hipGetDevice(&dev);
  int coop_attr = 0;
  (void)hipDeviceGetAttribute(&coop_attr, hipDeviceAttributeCooperativeLaunch, dev);
  int maxb = 0;
  (void)hipOccupancyMaxActiveBlocksPerMultiprocessor(
      &maxb, reinterpret_cast<const void*>(fused_all), 256, 0);

  bool done = false;
  if (coop_attr != 0 && maxb >= 2) {
    void* args[] = {(void*)&x,    (void*)&Kw,   (void*)&Vw,
                    (void*)&x16,  (void*)&K16,  (void*)&V16t,
                    (void*)&P16,  (void*)&lsum, (void*)&out};
    hipError_t e = hipLaunchCooperativeKernel((void*)fused_all, dim3(512),
                                              dim3(256), args, 0, stream);
    done = (e == hipSuccess);
  }

  if (!done) {
    cvt_all_k<<<7168, 256, 0, stream>>>(x, x16, Kw, K16, Vw, V16t, lsum);
    gemm1_k<<<dim3(32, 64), 256, 0, stream>>>(x16, K16, P16, lsum, sc);
    gemm2_k<<<512, 256, 0, stream>>>(P16, V16t, out, lsum);
  }
}